// Round 2
// baseline (449.978 us; speedup 1.0000x reference)
//
#include <hip/hip_runtime.h>
#include <cmath>

#define HW (512*512)
#define NBINS 64

// f(t) for Lab: t > eps ? cbrt(t) : 7.787t + 16/116
__device__ __forceinline__ float lab_f(float t) {
    // fast cbrt via exp2(log2(t)/3); t<=0 gives NaN/-inf path, discarded by select
    float cb = exp2f(log2f(t) * (1.0f / 3.0f));
    return (t > 0.008856f) ? cb : (7.787f * t + 16.0f / 116.0f);
}

// u = bin-space coordinate (bin j has center at u==j). Weight = exp(-2*(u-j)^2)
// = exp2(-(2/ln2)*(u-j)^2). Truncate at |u-j|<=3 (dropped mass ~1e-8 per pixel).
__device__ __forceinline__ void accum_bins(float* __restrict__ h, float u) {
    int jlo = (int)ceilf(u - 3.0f);
    int jhi = (int)floorf(u + 3.0f);
    jlo = max(jlo, 0);
    jhi = min(jhi, 63);
    const float C = 2.8853901f; // 2/ln(2)
    for (int j = jlo; j <= jhi; ++j) {
        float d = u - (float)j;
        atomicAdd(h + j, exp2f(-C * d * d));
    }
}

__global__ __launch_bounds__(256) void hist_kernel(const float* __restrict__ img,
                                                   float* __restrict__ hist) {
    __shared__ float sh[3 * NBINS];
    const int tid = threadIdx.x;
    for (int i = tid; i < 3 * NBINS; i += 256) sh[i] = 0.0f;
    __syncthreads();

    const int b = blockIdx.y;
    const float* base = img + (size_t)b * 3u * HW;

    const float invDL = 64.0f / 100.0f;   // 1/delta_L
    const float invDA = 64.0f / 255.0f;   // 1/delta_a == 1/delta_b

    for (int p = blockIdx.x * 256 + tid; p < HW; p += gridDim.x * 256) {
        float r  = base[p];
        float g  = base[p + HW];
        float bl = base[p + 2 * HW];

        // sRGB -> linear
        float lr = (r  > 0.04045f) ? exp2f(2.4f * log2f((r  + 0.055f) * (1.0f / 1.055f))) : r  * (1.0f / 12.92f);
        float lg = (g  > 0.04045f) ? exp2f(2.4f * log2f((g  + 0.055f) * (1.0f / 1.055f))) : g  * (1.0f / 12.92f);
        float lb = (bl > 0.04045f) ? exp2f(2.4f * log2f((bl + 0.055f) * (1.0f / 1.055f))) : bl * (1.0f / 12.92f);

        // linear RGB -> XYZ (D65), then normalize x,z
        float x = 0.412453f * lr + 0.35758f  * lg + 0.180423f * lb;
        float y = 0.212671f * lr + 0.71516f  * lg + 0.072169f * lb;
        float z = 0.019334f * lr + 0.119193f * lg + 0.950227f * lb;
        x *= (1.0f / 0.950456f);
        z *= (1.0f / 1.088754f);

        float fx = lab_f(x), fy = lab_f(y), fz = lab_f(z);
        float L  = 116.0f * fy - 16.0f;
        float a  = 500.0f * (fx - fy);
        float bb = 200.0f * (fy - fz);

        // bin-space coords: u = (v - vmin)/delta - 0.5
        accum_bins(sh,        L * invDL - 0.5f);
        accum_bins(sh + 64,   (a  + 128.0f) * invDA - 0.5f);
        accum_bins(sh + 128,  (bb + 128.0f) * invDA - 0.5f);
    }
    __syncthreads();

    for (int i = tid; i < 3 * NBINS; i += 256) {
        float v = sh[i];
        if (v != 0.0f) atomicAdd(hist + (size_t)b * 192 + i, v);
    }
}

__global__ __launch_bounds__(64) void norm_kernel(const float* __restrict__ hist,
                                                  float* __restrict__ out) {
    const int bc = blockIdx.x;   // 0..B*3-1 (image*3 + channel)
    const int t  = threadIdx.x;  // 0..63
    float v = hist[bc * 64 + t];
    float s = v;
    #pragma unroll
    for (int off = 32; off >= 1; off >>= 1) s += __shfl_down(s, off, 64);
    s = __shfl(s, 0, 64);
    out[bc * 64 + t] = v / (s + 1e-8f);
}

extern "C" void kernel_launch(void* const* d_in, const int* in_sizes, int n_in,
                              void* d_out, int out_size, void* d_ws, size_t ws_size,
                              hipStream_t stream) {
    const float* img = (const float*)d_in[0];
    float* out  = (float*)d_out;
    float* hist = (float*)d_ws;

    const int B = in_sizes[0] / (3 * HW);   // 16

    // workspace: B*192 f32 partial (unnormalized) histograms; harness poisons ws
    (void)hipMemsetAsync(hist, 0, (size_t)B * 192 * sizeof(float), stream);

    hist_kernel<<<dim3(64, B), 256, 0, stream>>>(img, hist);
    norm_kernel<<<B * 3, 64, 0, stream>>>(hist, out);
}

// Round 3
// 355.940 us; speedup vs baseline: 1.2642x; 1.2642x over previous
//
#include <hip/hip_runtime.h>
#include <cmath>

#define HW (512*512)
#define NBINS 64
#define MAX_PARTS 128
#define THREADS 256

// f(t) for Lab: t > eps ? cbrt(t) : 7.787t + 16/116
__device__ __forceinline__ float lab_f(float t) {
    float cb = exp2f(log2f(t) * (1.0f / 3.0f));
    return (t > 0.008856f) ? cb : (7.787f * t + 16.0f / 116.0f);
}

// Soft-histogram scatter in bin space (bin j center at u==j), weight exp(-2(u-j)^2)
// = exp2(-(2/ln2) d^2). Truncated at |d|<=2: exactly 4 bins (generic u), unrolled.
__device__ __forceinline__ void accum4(float* __restrict__ h, float u) {
    float jf = ceilf(u) - 2.0f;
    int j0 = (int)jf;
    float d0 = u - jf;              // in (1, 2]
    const float C = 2.8853901f;     // 2/ln(2)
#pragma unroll
    for (int k = 0; k < 4; ++k) {
        float d = d0 - (float)k;
        float w = exp2f(-C * d * d);
        int j = j0 + k;
        if ((unsigned)j < 64u) unsafeAtomicAdd(h + j, w);  // native ds_add_f32
    }
}

__global__ __launch_bounds__(THREADS) void hist_kernel(const float* __restrict__ img,
                                                       float* __restrict__ part,
                                                       int nparts) {
    __shared__ float sh[3 * NBINS];
    const int tid = threadIdx.x;
    for (int i = tid; i < 3 * NBINS; i += THREADS) sh[i] = 0.0f;
    __syncthreads();

    const int b  = blockIdx.y;
    const int bx = blockIdx.x;
    const float* base = img + (size_t)b * 3u * HW;

    const float invDL = 64.0f / 100.0f;
    const float invDA = 64.0f / 255.0f;

    for (int p = bx * THREADS + tid; p < HW; p += nparts * THREADS) {
        float r  = base[p];
        float g  = base[p + HW];
        float bl = base[p + 2 * HW];

        // sRGB -> linear
        float lr = (r  > 0.04045f) ? exp2f(2.4f * log2f((r  + 0.055f) * (1.0f / 1.055f))) : r  * (1.0f / 12.92f);
        float lg = (g  > 0.04045f) ? exp2f(2.4f * log2f((g  + 0.055f) * (1.0f / 1.055f))) : g  * (1.0f / 12.92f);
        float lb = (bl > 0.04045f) ? exp2f(2.4f * log2f((bl + 0.055f) * (1.0f / 1.055f))) : bl * (1.0f / 12.92f);

        // linear RGB -> XYZ (D65), normalize x,z
        float x = 0.412453f * lr + 0.35758f  * lg + 0.180423f * lb;
        float y = 0.212671f * lr + 0.71516f  * lg + 0.072169f * lb;
        float z = 0.019334f * lr + 0.119193f * lg + 0.950227f * lb;
        x *= (1.0f / 0.950456f);
        z *= (1.0f / 1.088754f);

        float fx = lab_f(x), fy = lab_f(y), fz = lab_f(z);
        float L  = 116.0f * fy - 16.0f;
        float a  = 500.0f * (fx - fy);
        float bb = 200.0f * (fy - fz);

        accum4(sh,       L * invDL - 0.5f);
        accum4(sh + 64,  (a  + 128.0f) * invDA - 0.5f);
        accum4(sh + 128, (bb + 128.0f) * invDA - 0.5f);
    }
    __syncthreads();

    // per-block partial histogram -> workspace (plain stores, no init needed)
    float* dst = part + ((size_t)b * nparts + bx) * 192;
    for (int i = tid; i < 3 * NBINS; i += THREADS) dst[i] = sh[i];
}

__global__ __launch_bounds__(64) void reduce_norm_kernel(const float* __restrict__ part,
                                                         float* __restrict__ out,
                                                         int nparts) {
    const int img = blockIdx.x / 3;
    const int ch  = blockIdx.x % 3;
    const int t   = threadIdx.x;

    const float* p = part + (size_t)img * nparts * 192 + ch * 64 + t;
    float v = 0.0f;
    for (int k = 0; k < nparts; ++k) v += p[(size_t)k * 192];

    float s = v;
    #pragma unroll
    for (int off = 32; off >= 1; off >>= 1) s += __shfl_down(s, off, 64);
    s = __shfl(s, 0, 64);

    out[img * 192 + ch * 64 + t] = v / (s + 1e-8f);
}

extern "C" void kernel_launch(void* const* d_in, const int* in_sizes, int n_in,
                              void* d_out, int out_size, void* d_ws, size_t ws_size,
                              hipStream_t stream) {
    const float* img = (const float*)d_in[0];
    float* out  = (float*)d_out;
    float* part = (float*)d_ws;

    const int B = in_sizes[0] / (3 * HW);   // 16

    // partials must fit in ws: B * nparts * 192 floats
    int nparts = (int)(ws_size / ((size_t)B * 192 * sizeof(float)));
    if (nparts > MAX_PARTS) nparts = MAX_PARTS;
    if (nparts < 1) nparts = 1;

    hist_kernel<<<dim3(nparts, B), THREADS, 0, stream>>>(img, part, nparts);
    reduce_norm_kernel<<<B * 3, 64, 0, stream>>>(part, out, nparts);
}

// Round 4
// 354.015 us; speedup vs baseline: 1.2711x; 1.0054x over previous
//
#include <hip/hip_runtime.h>
#include <cmath>

#define HW (512*512)
#define NBINS 64
#define NCOPIES 16
#define CSTRIDE 193   // 192 bins + 1 pad: copy c is bank-shifted by c -> hot bin spreads over 16 banks
#define MAX_PARTS 128
#define THREADS 256

// f(t) for Lab: t > eps ? cbrt(t) : 7.787t + 16/116
__device__ __forceinline__ float lab_f(float t) {
    float cb = exp2f(log2f(t) * (1.0f / 3.0f));
    return (t > 0.008856f) ? cb : (7.787f * t + 16.0f / 116.0f);
}

__device__ __forceinline__ float srgb_lin(float v) {
    return (v > 0.04045f) ? exp2f(2.4f * log2f((v + 0.055f) * (1.0f / 1.055f)))
                          : v * (1.0f / 12.92f);
}

// 4-bin truncated-gaussian scatter in bin space (bin j center at u==j).
// w_k = exp(-2(d0-k)^2) = e0 * t^k * exp(-2k^2), e0=exp(-2 d0^2), t=exp(4 d0).
// Only 2 transcendentals for all 4 weights.
__device__ __forceinline__ void accum4(float* __restrict__ h, float u) {
    float jf = ceilf(u) - 2.0f;
    int   j0 = (int)jf;
    float d0 = u - jf;                         // in (1, 2]
    const float C = 2.8853901f;                // 2/ln2
    float e0 = exp2f(-C * d0 * d0);            // exp(-2 d0^2)
    float t  = exp2f((2.0f * C) * d0);         // exp(4 d0)
    float t2 = t * t;
    float w0 = e0;
    float w1 = e0 * t  * 0.13533528f;          // e^-2
    float w2 = e0 * t2 * 3.3546262e-4f;        // e^-8
    float w3 = e0 * t2 * t * 1.5229979e-8f;    // e^-18
    if ((unsigned)(j0    ) < 64u) unsafeAtomicAdd(h + j0,     w0);
    if ((unsigned)(j0 + 1) < 64u) unsafeAtomicAdd(h + j0 + 1, w1);
    if ((unsigned)(j0 + 2) < 64u) unsafeAtomicAdd(h + j0 + 2, w2);
    if ((unsigned)(j0 + 3) < 64u) unsafeAtomicAdd(h + j0 + 3, w3);
}

__global__ __launch_bounds__(THREADS) void hist_kernel(const float* __restrict__ img,
                                                       float* __restrict__ part,
                                                       int nparts) {
    __shared__ float sh[NCOPIES * CSTRIDE];
    const int tid = threadIdx.x;
    for (int i = tid; i < NCOPIES * CSTRIDE; i += THREADS) sh[i] = 0.0f;
    __syncthreads();

    float* h = sh + (tid & (NCOPIES - 1)) * CSTRIDE;

    const int b  = blockIdx.y;
    const int bx = blockIdx.x;
    const float* base = img + (size_t)b * 3u * HW;

    const float invDL = 64.0f / 100.0f;
    const float invDA = 64.0f / 255.0f;

    const int stride = nparts * THREADS * 4;
    for (int p = (bx * THREADS + tid) * 4; p < HW; p += stride) {
        float4 r4 = *reinterpret_cast<const float4*>(base + p);
        float4 g4 = *reinterpret_cast<const float4*>(base + p + HW);
        float4 b4 = *reinterpret_cast<const float4*>(base + p + 2 * HW);
        float rr[4] = {r4.x, r4.y, r4.z, r4.w};
        float gg[4] = {g4.x, g4.y, g4.z, g4.w};
        float bl[4] = {b4.x, b4.y, b4.z, b4.w};

        #pragma unroll
        for (int k = 0; k < 4; ++k) {
            float lr = srgb_lin(rr[k]);
            float lg = srgb_lin(gg[k]);
            float lb = srgb_lin(bl[k]);

            float x = 0.412453f * lr + 0.35758f  * lg + 0.180423f * lb;
            float y = 0.212671f * lr + 0.71516f  * lg + 0.072169f * lb;
            float z = 0.019334f * lr + 0.119193f * lg + 0.950227f * lb;
            x *= (1.0f / 0.950456f);
            z *= (1.0f / 1.088754f);

            float fx = lab_f(x), fy = lab_f(y), fz = lab_f(z);
            float L  = 116.0f * fy - 16.0f;
            float a  = 500.0f * (fx - fy);
            float bb = 200.0f * (fy - fz);

            accum4(h,        L * invDL - 0.5f);
            accum4(h + 64,   (a  + 128.0f) * invDA - 0.5f);
            accum4(h + 128,  (bb + 128.0f) * invDA - 0.5f);
        }
    }
    __syncthreads();

    // merge the 16 privatized copies -> per-block partial histogram (plain stores)
    float* dst = part + ((size_t)b * nparts + bx) * 192;
    for (int i = tid; i < 192; i += THREADS) {
        float s = 0.0f;
        #pragma unroll
        for (int c = 0; c < NCOPIES; ++c) s += sh[c * CSTRIDE + i];
        dst[i] = s;
    }
}

__global__ __launch_bounds__(64) void reduce_norm_kernel(const float* __restrict__ part,
                                                         float* __restrict__ out,
                                                         int nparts) {
    const int img = blockIdx.x / 3;
    const int ch  = blockIdx.x % 3;
    const int t   = threadIdx.x;

    const float* p = part + (size_t)img * nparts * 192 + ch * 64 + t;
    float v = 0.0f;
    for (int k = 0; k < nparts; ++k) v += p[(size_t)k * 192];

    float s = v;
    #pragma unroll
    for (int off = 32; off >= 1; off >>= 1) s += __shfl_down(s, off, 64);
    s = __shfl(s, 0, 64);

    out[img * 192 + ch * 64 + t] = v / (s + 1e-8f);
}

extern "C" void kernel_launch(void* const* d_in, const int* in_sizes, int n_in,
                              void* d_out, int out_size, void* d_ws, size_t ws_size,
                              hipStream_t stream) {
    const float* img = (const float*)d_in[0];
    float* out  = (float*)d_out;
    float* part = (float*)d_ws;

    const int B = in_sizes[0] / (3 * HW);   // 16

    int nparts = (int)(ws_size / ((size_t)B * 192 * sizeof(float)));
    if (nparts > MAX_PARTS) nparts = MAX_PARTS;
    if (nparts < 1) nparts = 1;

    hist_kernel<<<dim3(nparts, B), THREADS, 0, stream>>>(img, part, nparts);
    reduce_norm_kernel<<<B * 3, 64, 0, stream>>>(part, out, nparts);
}

// Round 5
// 110.639 us; speedup vs baseline: 4.0671x; 3.1997x over previous
//
#include <hip/hip_runtime.h>
#include <cmath>

#define HW (512*512)
#define NSUB 2048            // 64 bins x 32 sub-bins
#define THREADS1 1024
#define BLKS_PER_IMG 32

__device__ __forceinline__ float srgb_lin(float v) {
    return (v > 0.04045f) ? exp2f(2.4f * log2f((v + 0.055f) * (1.0f / 1.055f)))
                          : v * (1.0f / 12.92f);
}

__device__ __forceinline__ float lab_f(float t) {
    float cb = exp2f(log2f(t) * (1.0f / 3.0f));
    return (t > 0.008856f) ? cb : (7.787f * t + 16.0f / 116.0f);
}

// Phase 1: integer sub-bin counting. 3 ds_add_u32 per pixel (vs 12 ds_add_f32).
__global__ __launch_bounds__(THREADS1) void count_kernel(const float* __restrict__ img,
                                                         unsigned* __restrict__ cnt) {
    __shared__ unsigned sh[3 * NSUB];   // 24 KB
    const int tid = threadIdx.x;
    for (int i = tid; i < 3 * NSUB; i += THREADS1) sh[i] = 0u;
    __syncthreads();

    const int b  = blockIdx.y;
    const int bx = blockIdx.x;
    const float* base = img + (size_t)b * 3u * HW;

    const float sL = (float)NSUB / 100.0f;   // sub-bins per unit L
    const float sA = (float)NSUB / 255.0f;   // sub-bins per unit a/b

    const int stride = BLKS_PER_IMG * THREADS1 * 4;
    for (int p = (bx * THREADS1 + tid) * 4; p < HW; p += stride) {
        float4 r4 = *reinterpret_cast<const float4*>(base + p);
        float4 g4 = *reinterpret_cast<const float4*>(base + p + HW);
        float4 b4 = *reinterpret_cast<const float4*>(base + p + 2 * HW);
        float rr[4] = {r4.x, r4.y, r4.z, r4.w};
        float gg[4] = {g4.x, g4.y, g4.z, g4.w};
        float bl[4] = {b4.x, b4.y, b4.z, b4.w};

        #pragma unroll
        for (int k = 0; k < 4; ++k) {
            float lr = srgb_lin(rr[k]);
            float lg = srgb_lin(gg[k]);
            float lb = srgb_lin(bl[k]);

            float x = 0.412453f * lr + 0.35758f  * lg + 0.180423f * lb;
            float y = 0.212671f * lr + 0.71516f  * lg + 0.072169f * lb;
            float z = 0.019334f * lr + 0.119193f * lg + 0.950227f * lb;
            x *= (1.0f / 0.950456f);
            z *= (1.0f / 1.088754f);

            float fx = lab_f(x), fy = lab_f(y), fz = lab_f(z);
            float L  = 116.0f * fy - 16.0f;
            float a  = 500.0f * (fx - fy);
            float bb = 200.0f * (fy - fz);

            int iL = (int)(L * sL);
            int iA = (int)((a  + 128.0f) * sA);
            int iB = (int)((bb + 128.0f) * sA);
            iL = min(max(iL, 0), NSUB - 1);
            iA = min(max(iA, 0), NSUB - 1);
            iB = min(max(iB, 0), NSUB - 1);

            atomicAdd(&sh[iL], 1u);
            atomicAdd(&sh[NSUB + iA], 1u);
            atomicAdd(&sh[2 * NSUB + iB], 1u);
        }
    }
    __syncthreads();

    // skip-zero global merge into per-image count accumulator
    unsigned* dst = cnt + (size_t)b * 3 * NSUB;
    for (int i = tid; i < 3 * NSUB; i += THREADS1) {
        unsigned v = sh[i];
        if (v) atomicAdd(dst + i, v);
    }
}

// Phase 2: dense Gaussian convolution of sub-bin counts -> 64 bins, normalize.
// weight(d bins) = exp(-2 d^2) = exp2(-(2/ln2) d^2); sub-bin s center in bin
// units: u_s = (s+0.5)/32 - 0.5.
__global__ __launch_bounds__(256) void conv_norm_kernel(const unsigned* __restrict__ cnt,
                                                        float* __restrict__ out) {
    __shared__ float sub[NSUB];
    __shared__ float hb[64];
    const int img = blockIdx.x / 3;
    const int ch  = blockIdx.x % 3;
    const int t   = threadIdx.x;

    const unsigned* src = cnt + ((size_t)img * 3 + ch) * NSUB;
    for (int i = t; i < NSUB; i += 256) sub[i] = (float)src[i];
    __syncthreads();

    const int j = t >> 2;                  // bin 0..63
    const int q = t & 3;                   // quarter 0..3
    const float C = 2.8853901f;            // 2/ln2
    const float jf = (float)j + 0.5f - (0.5f / 32.0f); // fold the +0.5 center shift
    float acc = 0.0f;
    // per-q index rotation de-conflicts LDS banks across the 4 lanes of a bin
    for (int i = 0; i < 512; ++i) {
        int s = q * 512 + ((i + q * 8) & 511);
        float d = (float)s * (1.0f / 32.0f) - jf;
        acc += sub[s] * exp2f(-C * d * d);
    }
    acc += __shfl_xor(acc, 1, 64);
    acc += __shfl_xor(acc, 2, 64);
    if (q == 0) hb[j] = acc;
    __syncthreads();

    if (t < 64) {
        float v = hb[t];
        float s = v;
        #pragma unroll
        for (int off = 32; off >= 1; off >>= 1) s += __shfl_down(s, off, 64);
        s = __shfl(s, 0, 64);
        out[img * 192 + ch * 64 + t] = v / (s + 1e-8f);
    }
}

extern "C" void kernel_launch(void* const* d_in, const int* in_sizes, int n_in,
                              void* d_out, int out_size, void* d_ws, size_t ws_size,
                              hipStream_t stream) {
    const float* img = (const float*)d_in[0];
    float* out    = (float*)d_out;
    unsigned* cnt = (unsigned*)d_ws;       // 16 * 3 * 2048 u32 = 384 KB

    const int B = in_sizes[0] / (3 * HW);  // 16

    (void)hipMemsetAsync(cnt, 0, (size_t)B * 3 * NSUB * sizeof(unsigned), stream);
    count_kernel<<<dim3(BLKS_PER_IMG, B), THREADS1, 0, stream>>>(img, cnt);
    conv_norm_kernel<<<B * 3, 256, 0, stream>>>(cnt, out);
}

// Round 6
// 100.472 us; speedup vs baseline: 4.4787x; 1.1012x over previous
//
#include <hip/hip_runtime.h>
#include <cmath>

#define HW (512*512)
#define NSUB 2048            // 64 bins x 32 sub-bins
#define THREADS1 512
#define BLKS_PER_IMG 64

// Phase 1: RGB -> Lab -> integer sub-bin counting. 3 ds_add_u32 per pixel.
__global__ __launch_bounds__(THREADS1) void count_kernel(const float* __restrict__ img,
                                                         unsigned* __restrict__ cnt) {
    __shared__ unsigned sh[3 * NSUB];   // 24 KB
    const int tid = threadIdx.x;
    for (int i = tid; i < 3 * NSUB; i += THREADS1) sh[i] = 0u;
    __syncthreads();

    const int b  = blockIdx.y;
    const int bx = blockIdx.x;
    const float* base = img + (size_t)b * 3u * HW;

    const int stride = BLKS_PER_IMG * THREADS1 * 4;
    for (int p = (bx * THREADS1 + tid) * 4; p < HW; p += stride) {
        float4 r4 = *reinterpret_cast<const float4*>(base + p);
        float4 g4 = *reinterpret_cast<const float4*>(base + p + HW);
        float4 b4 = *reinterpret_cast<const float4*>(base + p + 2 * HW);
        float rr[4] = {r4.x, r4.y, r4.z, r4.w};
        float gg[4] = {g4.x, g4.y, g4.z, g4.w};
        float bl[4] = {b4.x, b4.y, b4.z, b4.w};

        #pragma unroll
        for (int k = 0; k < 4; ++k) {
            // sRGB -> linear
            float lr = (rr[k] > 0.04045f) ? exp2f(2.4f * log2f((rr[k] + 0.055f) * (1.0f / 1.055f))) : rr[k] * (1.0f / 12.92f);
            float lg = (gg[k] > 0.04045f) ? exp2f(2.4f * log2f((gg[k] + 0.055f) * (1.0f / 1.055f))) : gg[k] * (1.0f / 12.92f);
            float lb = (bl[k] > 0.04045f) ? exp2f(2.4f * log2f((bl[k] + 0.055f) * (1.0f / 1.055f))) : bl[k] * (1.0f / 12.92f);

            // XYZ with xn/zn folded into the matrix rows
            float x = 0.4339530f * lr + 0.3762197f * lg + 0.1898288f * lb; // x/0.950456
            float y = 0.2126710f * lr + 0.7151600f * lg + 0.0721690f * lb;
            float z = 0.0177578f * lr + 0.1094766f * lg + 0.8727661f * lb; // z/1.088754

            float fx = (x > 0.008856f) ? exp2f(log2f(x) * (1.0f/3.0f)) : 7.787f * x + 16.0f/116.0f;
            float fy = (y > 0.008856f) ? exp2f(log2f(y) * (1.0f/3.0f)) : 7.787f * y + 16.0f/116.0f;
            float fz = (z > 0.008856f) ? exp2f(log2f(z) * (1.0f/3.0f)) : 7.787f * z + 16.0f/116.0f;

            // sub-bin indices, scale/offset folded; ranges provably in [0,2048) -> no clamps
            // iL = (116 fy - 16) * 20.48 ; iA = (500(fx-fy)+128)*8.0313725 ; iB = (200(fy-fz)+128)*...
            int iL = (int)(2375.68f    * fy - 327.68f);
            int iA = (int)(4015.6863f  * (fx - fy) + 1028.01569f);
            int iB = (int)(1606.27451f * (fy - fz) + 1028.01569f);

            atomicAdd(&sh[iL], 1u);
            atomicAdd(&sh[NSUB + iA], 1u);
            atomicAdd(&sh[2 * NSUB + iB], 1u);
        }
    }
    __syncthreads();

    unsigned* dst = cnt + (size_t)b * 3 * NSUB;
    for (int i = tid; i < 3 * NSUB; i += THREADS1) {
        unsigned v = sh[i];
        if (v) atomicAdd(dst + i, v);
    }
}

// Phase 2: truncated Gaussian conv of sub-bin counts -> 64 bins, normalize.
// d(s,j) = (s+0.5)/32 - 0.5 - j; zero at s* = 32j+15.5; keep |s-s*| <= 102 (204 taps).
__global__ __launch_bounds__(256) void conv_norm_kernel(const unsigned* __restrict__ cnt,
                                                        float* __restrict__ out) {
    __shared__ float sub[NSUB];
    __shared__ float hb[64];
    const int img = blockIdx.x / 3;
    const int ch  = blockIdx.x % 3;
    const int t   = threadIdx.x;

    const unsigned* src = cnt + ((size_t)img * 3 + ch) * NSUB;
    for (int i = t; i < NSUB; i += 256) sub[i] = (float)src[i];
    __syncthreads();

    const int j = t >> 2;                  // bin 0..63
    const int q = t & 3;                   // quarter 0..3
    const float C = 2.8853901f;            // 2/ln2
    const float jf = (float)j + 0.5f - (0.5f / 32.0f);
    const int s_lo = 32 * j - 86;          // window start (204 taps, 51 per q-lane)
    float acc = 0.0f;
    for (int i = 0; i < 51; ++i) {
        int ii = i + j; if (ii >= 51) ii -= 51;          // per-j rotation: de-banks lanes
        int s  = s_lo + q + 4 * ii;
        if ((unsigned)s < (unsigned)NSUB) {
            float d = (float)s * (1.0f / 32.0f) - jf;
            acc += sub[s] * exp2f(-C * d * d);
        }
    }
    acc += __shfl_xor(acc, 1, 64);
    acc += __shfl_xor(acc, 2, 64);
    if (q == 0) hb[j] = acc;
    __syncthreads();

    if (t < 64) {
        float v = hb[t];
        float s = v;
        #pragma unroll
        for (int off = 32; off >= 1; off >>= 1) s += __shfl_down(s, off, 64);
        s = __shfl(s, 0, 64);
        out[img * 192 + ch * 64 + t] = v / (s + 1e-8f);
    }
}

extern "C" void kernel_launch(void* const* d_in, const int* in_sizes, int n_in,
                              void* d_out, int out_size, void* d_ws, size_t ws_size,
                              hipStream_t stream) {
    const float* img = (const float*)d_in[0];
    float* out    = (float*)d_out;
    unsigned* cnt = (unsigned*)d_ws;       // 16 * 3 * 2048 u32 = 384 KB

    const int B = in_sizes[0] / (3 * HW);  // 16

    (void)hipMemsetAsync(cnt, 0, (size_t)B * 3 * NSUB * sizeof(unsigned), stream);
    count_kernel<<<dim3(BLKS_PER_IMG, B), THREADS1, 0, stream>>>(img, cnt);
    conv_norm_kernel<<<B * 3, 256, 0, stream>>>(cnt, out);
}

// Round 7
// 96.923 us; speedup vs baseline: 4.6426x; 1.0366x over previous
//
#include <hip/hip_runtime.h>
#include <cmath>

#define HW (512*512)
#define NSUB 2048            // 64 bins x 32 sub-bins
#define THREADS1 1024
#define BLKS_PER_IMG 32

// Phase 1: RGB -> Lab -> integer sub-bin counting into dual wave-parity LDS
// tables (3 ds_add_u32 per pixel, halved cross-wave contention). Per-block
// partial tables written to ws with plain stores (no global atomics).
__global__ __launch_bounds__(THREADS1) void count_kernel(const float* __restrict__ img,
                                                         unsigned* __restrict__ part) {
    __shared__ unsigned sh[2][3 * NSUB];   // 48 KB
    const int tid = threadIdx.x;
    unsigned* flat = &sh[0][0];
    for (int i = tid; i < 2 * 3 * NSUB; i += THREADS1) flat[i] = 0u;
    __syncthreads();

    unsigned* h = sh[(tid >> 6) & 1];      // wave parity selects table

    const int b  = blockIdx.y;
    const int bx = blockIdx.x;
    const float* base = img + (size_t)b * 3u * HW;

    const int stride = BLKS_PER_IMG * THREADS1 * 4;
    for (int p = (bx * THREADS1 + tid) * 4; p < HW; p += stride) {
        float4 r4 = *reinterpret_cast<const float4*>(base + p);
        float4 g4 = *reinterpret_cast<const float4*>(base + p + HW);
        float4 b4 = *reinterpret_cast<const float4*>(base + p + 2 * HW);
        float rr[4] = {r4.x, r4.y, r4.z, r4.w};
        float gg[4] = {g4.x, g4.y, g4.z, g4.w};
        float bl[4] = {b4.x, b4.y, b4.z, b4.w};

        #pragma unroll
        for (int k = 0; k < 4; ++k) {
            // sRGB -> linear
            float lr = (rr[k] > 0.04045f) ? exp2f(2.4f * log2f((rr[k] + 0.055f) * (1.0f / 1.055f))) : rr[k] * (1.0f / 12.92f);
            float lg = (gg[k] > 0.04045f) ? exp2f(2.4f * log2f((gg[k] + 0.055f) * (1.0f / 1.055f))) : gg[k] * (1.0f / 12.92f);
            float lb = (bl[k] > 0.04045f) ? exp2f(2.4f * log2f((bl[k] + 0.055f) * (1.0f / 1.055f))) : bl[k] * (1.0f / 12.92f);

            // XYZ with xn/zn folded into the matrix rows
            float x = 0.4339530f * lr + 0.3762197f * lg + 0.1898288f * lb; // x/0.950456
            float y = 0.2126710f * lr + 0.7151600f * lg + 0.0721690f * lb;
            float z = 0.0177578f * lr + 0.1094766f * lg + 0.8727661f * lb; // z/1.088754

            float fx = (x > 0.008856f) ? exp2f(log2f(x) * (1.0f/3.0f)) : 7.787f * x + 16.0f/116.0f;
            float fy = (y > 0.008856f) ? exp2f(log2f(y) * (1.0f/3.0f)) : 7.787f * y + 16.0f/116.0f;
            float fz = (z > 0.008856f) ? exp2f(log2f(z) * (1.0f/3.0f)) : 7.787f * z + 16.0f/116.0f;

            // sub-bin indices (scale/offset folded); ranges provably in [0,2048)
            int iL = (int)(2375.68f    * fy - 327.68f);
            int iA = (int)(4015.6863f  * (fx - fy) + 1028.01569f);
            int iB = (int)(1606.27451f * (fy - fz) + 1028.01569f);

            atomicAdd(&h[iL], 1u);
            atomicAdd(&h[NSUB + iA], 1u);
            atomicAdd(&h[2 * NSUB + iB], 1u);
        }
    }
    __syncthreads();

    // merge dual tables -> per-block partial (plain coalesced stores)
    unsigned* dst = part + ((size_t)(b * BLKS_PER_IMG + bx)) * 3 * NSUB;
    for (int i = tid; i < 3 * NSUB; i += THREADS1) dst[i] = sh[0][i] + sh[1][i];
}

// Phase 2: reduce 32 per-block partials, truncated Gaussian conv -> 64 bins,
// normalize. d(s,j) = (s+0.5)/32 - 0.5 - j; keep 204 taps around s* = 32j+15.5.
__global__ __launch_bounds__(256) void conv_norm_kernel(const unsigned* __restrict__ part,
                                                        float* __restrict__ out) {
    __shared__ float sub[NSUB];
    __shared__ float hb[64];
    const int img = blockIdx.x / 3;
    const int ch  = blockIdx.x % 3;
    const int t   = threadIdx.x;

    // each thread reduces 8 consecutive sub-bins across the 32 partials
    const unsigned* p0 = part + (size_t)img * BLKS_PER_IMG * 3 * NSUB + (size_t)ch * NSUB;
    float acc8[8] = {0,0,0,0,0,0,0,0};
    for (int k = 0; k < BLKS_PER_IMG; ++k) {
        const unsigned* pk = p0 + (size_t)k * 3 * NSUB + t * 8;
        uint4 a = *reinterpret_cast<const uint4*>(pk);
        uint4 c = *reinterpret_cast<const uint4*>(pk + 4);
        acc8[0] += (float)a.x; acc8[1] += (float)a.y;
        acc8[2] += (float)a.z; acc8[3] += (float)a.w;
        acc8[4] += (float)c.x; acc8[5] += (float)c.y;
        acc8[6] += (float)c.z; acc8[7] += (float)c.w;
    }
    #pragma unroll
    for (int i = 0; i < 8; ++i) sub[t * 8 + i] = acc8[i];
    __syncthreads();

    const int j = t >> 2;                  // bin 0..63
    const int q = t & 3;                   // quarter 0..3
    const float C = 2.8853901f;            // 2/ln2
    const float jf = (float)j + 0.5f - (0.5f / 32.0f);
    const int s_lo = 32 * j - 86;          // 204-tap window, 51 per q-lane
    float acc = 0.0f;
    for (int i = 0; i < 51; ++i) {
        int ii = i + j; if (ii >= 51) ii -= 51;   // per-j rotation de-banks lanes
        int s  = s_lo + q + 4 * ii;
        if ((unsigned)s < (unsigned)NSUB) {
            float d = (float)s * (1.0f / 32.0f) - jf;
            acc += sub[s] * exp2f(-C * d * d);
        }
    }
    acc += __shfl_xor(acc, 1, 64);
    acc += __shfl_xor(acc, 2, 64);
    if (q == 0) hb[j] = acc;
    __syncthreads();

    if (t < 64) {
        float v = hb[t];
        float s = v;
        #pragma unroll
        for (int off = 32; off >= 1; off >>= 1) s += __shfl_down(s, off, 64);
        s = __shfl(s, 0, 64);
        out[img * 192 + ch * 64 + t] = v / (s + 1e-8f);
    }
}

extern "C" void kernel_launch(void* const* d_in, const int* in_sizes, int n_in,
                              void* d_out, int out_size, void* d_ws, size_t ws_size,
                              hipStream_t stream) {
    const float* img = (const float*)d_in[0];
    float* out     = (float*)d_out;
    unsigned* part = (unsigned*)d_ws;     // 16*32 blocks * 3*2048 u32 = 12.6 MB

    const int B = in_sizes[0] / (3 * HW); // 16

    count_kernel<<<dim3(BLKS_PER_IMG, B), THREADS1, 0, stream>>>(img, part);
    conv_norm_kernel<<<B * 3, 256, 0, stream>>>(part, out);
}